// Round 4
// baseline (7535.490 us; speedup 1.0000x reference)
//
#include <hip/hip_runtime.h>
#include <math.h>

// ---------------------------------------------------------------------------
// Sizes (fixed by the problem)
// ---------------------------------------------------------------------------
#define D 768
#define NPARA 32
#define LPARA 512
#define LQ 32
#define NENT 10000
#define MMENT 30000
#define NPAIR 20000
#define NSTEP 3
#define CHUNK 10000   // row chunk for the 20000-row MLPs

__device__ __forceinline__ float geluf(float x) {
    return 0.5f * x * (1.0f + erff(x * 0.70710678118654752f));
}

// ---------------------------------------------------------------------------
// Tiled fp32 GEMM: C[M,N] = act(A[M,K] @ W[K,N] + bias)
// MODE 0: A = plain row-major pointer
// MODE 1: A row r = concat(para[p,t1,:], para[p,t2,:]) with (p,t1,t2) from
//         ppos row r columns (0, c1, c2). K must be 1536.
// MODE 2: A row r, col k: s=k/768, kk=k%768, from Sf/Of (rows x 768):
//         s==0: Sf, s==1: Of, s==2: Of-Sf, s==3: Sf*Of. K must be 3072.
// ACT 0: none, 1: gelu
// ---------------------------------------------------------------------------
#define GBM 128
#define GBN 128
#define GBK 8

template <int MODE, int ACT>
__global__ __launch_bounds__(256) void gemm_k(
    const float* __restrict__ A,
    const float* __restrict__ para,
    const int* __restrict__ ppos, int c1, int c2,
    const float* __restrict__ Sf, const float* __restrict__ Of,
    const float* __restrict__ W, const float* __restrict__ bias,
    float* __restrict__ C, int M, int N, int K)
{
    __shared__ float As[GBK][GBM + 4];
    __shared__ float Bs[GBK][GBN];
    __shared__ int baseL[GBM];
    __shared__ int baseR[GBM];

    const int tid = threadIdx.x;
    const int m0 = blockIdx.x * GBM;
    const int n0 = blockIdx.y * GBN;

    if (MODE == 1) {
        if (tid < GBM) {
            int gm = m0 + tid;
            int p = 0, t1 = 0, t2 = 0;
            if (gm < M) {
                p = ppos[gm * 5];
                t1 = ppos[gm * 5 + c1];
                t2 = ppos[gm * 5 + c2];
            }
            baseL[tid] = (p * LPARA + t1) * D;
            baseR[tid] = (p * LPARA + t2) * D;
        }
        __syncthreads();
    }

    const int tx = tid & 15;
    const int ty = tid >> 4;

    float acc[8][8];
#pragma unroll
    for (int i = 0; i < 8; ++i)
#pragma unroll
        for (int j = 0; j < 8; ++j) acc[i][j] = 0.0f;

    const int nkt = K / GBK;
    for (int kt = 0; kt < nkt; ++kt) {
        const int k0 = kt * GBK;
        // --- load A tile (128 x 8) ---
#pragma unroll
        for (int i = 0; i < 4; ++i) {
            int idx = tid + i * 256;
            int m = idx >> 3, k = idx & 7;
            int gm = m0 + m;
            float v = 0.0f;
            if (gm < M) {
                int kk = k0 + k;
                if (MODE == 0) {
                    v = A[(size_t)gm * K + kk];
                } else if (MODE == 1) {
                    v = (kk < D) ? para[baseL[m] + kk] : para[baseR[m] + kk - D];
                } else {
                    int s = kk / D;
                    int r = kk - s * D;
                    float sv = Sf[(size_t)gm * D + r];
                    float ov = Of[(size_t)gm * D + r];
                    v = (s == 0) ? sv : (s == 1) ? ov : (s == 2) ? (ov - sv) : (sv * ov);
                }
            }
            As[k][m] = v;
        }
        // --- load B tile (8 x 128); N multiple of 128, K of 8 ---
#pragma unroll
        for (int i = 0; i < 4; ++i) {
            int idx = tid + i * 256;
            int k = idx >> 7, n = idx & 127;
            Bs[k][n] = W[(size_t)(k0 + k) * N + n0 + n];
        }
        __syncthreads();
#pragma unroll
        for (int k = 0; k < GBK; ++k) {
            float a[8], b[8];
#pragma unroll
            for (int i = 0; i < 8; ++i) a[i] = As[k][ty * 8 + i];
#pragma unroll
            for (int j = 0; j < 8; ++j) b[j] = Bs[k][tx * 8 + j];
#pragma unroll
            for (int i = 0; i < 8; ++i)
#pragma unroll
                for (int j = 0; j < 8; ++j) acc[i][j] = fmaf(a[i], b[j], acc[i][j]);
        }
        __syncthreads();
    }

#pragma unroll
    for (int i = 0; i < 8; ++i) {
        int gm = m0 + ty * 8 + i;
        if (gm >= M) continue;
#pragma unroll
        for (int j = 0; j < 8; ++j) {
            int gn = n0 + tx * 8 + j;
            float v = acc[i][j] + bias[gn];
            if (ACT == 1) v = geluf(v);
            C[(size_t)gm * N + gn] = v;
        }
    }
}

// ---------------------------------------------------------------------------
// Per-entity mention mean: out[e,0:768]=mean(left), out[e,768:1536]=mean(right)
// ---------------------------------------------------------------------------
__global__ __launch_bounds__(256) void k_entmean(
    const float* __restrict__ para, const int* __restrict__ mpos,
    const int* __restrict__ mid, int M, float* __restrict__ out)
{
    __shared__ int sb[2];
    const int e = blockIdx.x;
    if (threadIdx.x < 2) {
        int target = e + threadIdx.x;
        int lo = 0, hi = M;
        while (lo < hi) {
            int md = (lo + hi) >> 1;
            if (mid[md] < target) lo = md + 1; else hi = md;
        }
        sb[threadIdx.x] = lo;
    }
    __syncthreads();
    const int lo = sb[0], hi = sb[1];
    const int tid = threadIdx.x;
    float a0 = 0, a1 = 0, a2 = 0, b0 = 0, b1 = 0, b2 = 0;
    for (int m = lo; m < hi; ++m) {
        int p = mpos[m * 3], t1 = mpos[m * 3 + 1], t2 = mpos[m * 3 + 2];
        const float* L = para + (size_t)(p * LPARA + t1) * D;
        const float* R = para + (size_t)(p * LPARA + t2) * D;
        a0 += L[tid]; a1 += L[tid + 256]; a2 += L[tid + 512];
        b0 += R[tid]; b1 += R[tid + 256]; b2 += R[tid + 512];
    }
    const float inv = (hi > lo) ? 1.0f / (float)(hi - lo) : 0.0f;
    float* o = out + (size_t)e * (2 * D);
    o[tid] = a0 * inv; o[tid + 256] = a1 * inv; o[tid + 512] = a2 * inv;
    o[D + tid] = b0 * inv; o[D + tid + 256] = b1 * inv; o[D + tid + 512] = b2 * inv;
}

// out[j] = act(sum_k x[k]*W[k*N+j] + b[j])
__global__ void k_vecmat(const float* __restrict__ x, const float* __restrict__ W,
                         const float* __restrict__ b, float* __restrict__ out,
                         int K, int N, int act)
{
    int j = blockIdx.x * blockDim.x + threadIdx.x;
    if (j >= N) return;
    float s = 0.0f;
    for (int k = 0; k < K; ++k) s = fmaf(x[k], W[(size_t)k * N + j], s);
    s += b[j];
    if (act) s = geluf(s);
    out[j] = s;
}

// ctx = softmax(cq . qwh_l) @ qwh + cq   (L=32 rows of 768)
__global__ void k_ctx(const float* __restrict__ cq, const float* __restrict__ qwh,
                      float* __restrict__ ctx)
{
    __shared__ float red[256];
    __shared__ float dist[LQ];
    const int tid = threadIdx.x;
    const int l = tid >> 3, part = tid & 7;
    float s = 0.0f;
    for (int d = part; d < D; d += 8) s += cq[d] * qwh[l * D + d];
    red[tid] = s;
    __syncthreads();
    if (part == 0) {
        float v = 0;
        for (int i = 0; i < 8; ++i) v += red[l * 8 + i];
        dist[l] = v;
    }
    __syncthreads();
    if (tid == 0) {
        float mx = -1e30f;
        for (int i = 0; i < LQ; ++i) mx = fmaxf(mx, dist[i]);
        float sm = 0;
        for (int i = 0; i < LQ; ++i) { float e = expf(dist[i] - mx); dist[i] = e; sm += e; }
        float inv = 1.0f / sm;
        for (int i = 0; i < LQ; ++i) dist[i] *= inv;
    }
    __syncthreads();
    for (int d = tid; d < D; d += 256) {
        float v = 0;
#pragma unroll
        for (int l2 = 0; l2 < LQ; ++l2) v += dist[l2] * qwh[l2 * D + d];
        ctx[d] = v + cq[d];
    }
}

// W1s[k,j] = ctx[k] * sW1[k,j]
__global__ void k_scalew(const float* __restrict__ ctx, const float* __restrict__ w1,
                         float* __restrict__ o, int n)
{
    int i = blockIdx.x * 256 + threadIdx.x;
    if (i < n) o[i] = ctx[i >> 8] * w1[i];
}

// sim[r] = sum_j H[r,j]*w2[j] + sb2;  PAIRMODE: sigmoid, gather, atomic scatter
template <int PAIRMODE>
__global__ void k_rowdot(const float* __restrict__ H, const float* __restrict__ w2,
                         const float* __restrict__ sb2, int Nr,
                         float* __restrict__ simout,
                         const float* __restrict__ laste, const int* __restrict__ so,
                         float* __restrict__ newe)
{
    int r = blockIdx.x * 4 + (threadIdx.x >> 6);
    int lane = threadIdx.x & 63;
    if (r >= Nr) return;
    float s = 0.0f;
#pragma unroll
    for (int i = 0; i < 4; ++i)
        s += H[(size_t)r * 256 + lane + i * 64] * w2[lane + i * 64];
    for (int off = 32; off > 0; off >>= 1) s += __shfl_down(s, off, 64);
    if (lane == 0) {
        s += sb2[0];
        if (PAIRMODE == 0) {
            simout[r] = s;
        } else {
            float p = 1.0f / (1.0f + expf(-s));
            float v = laste[so[r * 2]] * p;
            atomicAdd(&newe[so[r * 2 + 1]], v);
        }
    }
}

// single-block softmax over n (=10000), with /max(v,1) clamp
__global__ void k_softmax(const float* __restrict__ sim, float* __restrict__ outp, int n)
{
    __shared__ float red[256];
    __shared__ float s_mx, s_sum;
    const int tid = threadIdx.x;
    float mx = -1e30f;
    for (int i = tid; i < n; i += 256) mx = fmaxf(mx, sim[i]);
    red[tid] = mx; __syncthreads();
    for (int off = 128; off > 0; off >>= 1) {
        if (tid < off) red[tid] = fmaxf(red[tid], red[tid + off]);
        __syncthreads();
    }
    if (tid == 0) s_mx = red[0];
    __syncthreads();
    const float mxv = s_mx;
    float sum = 0;
    for (int i = tid; i < n; i += 256) sum += expf(sim[i] - mxv);
    red[tid] = sum; __syncthreads();
    for (int off = 128; off > 0; off >>= 1) {
        if (tid < off) red[tid] += red[tid + off];
        __syncthreads();
    }
    if (tid == 0) s_sum = red[0];
    __syncthreads();
    const float inv = 1.0f / s_sum;
    for (int i = tid; i < n; i += 256) {
        float v = expf(sim[i] - mxv) * inv;
        outp[i] = v / fmaxf(v, 1.0f);
    }
}

__global__ void k_zero(float* p, int n)
{
    int i = blockIdx.x * blockDim.x + threadIdx.x;
    if (i < n) p[i] = 0.0f;
}

__global__ void k_clampstore(const float* __restrict__ ne, float* __restrict__ outp, int n)
{
    int i = blockIdx.x * blockDim.x + threadIdx.x;
    if (i < n) { float v = ne[i]; outp[i] = v / fmaxf(v, 1.0f); }
}

// out[i] = softmax(hlog)[t] . probs[t][i]
__global__ void k_final(const float* __restrict__ probs, const float* __restrict__ hlog,
                        float* __restrict__ out, int n)
{
    int i = blockIdx.x * blockDim.x + threadIdx.x;
    if (i >= n) return;
    float l0 = hlog[0], l1 = hlog[1], l2 = hlog[2];
    float m = fmaxf(l0, fmaxf(l1, l2));
    float e0 = expf(l0 - m), e1 = expf(l1 - m), e2 = expf(l2 - m);
    float inv = 1.0f / (e0 + e1 + e2);
    out[i] = (e0 * probs[i] + e1 * probs[n + i] + e2 * probs[2 * n + i]) * inv;
}

// ---------------------------------------------------------------------------
extern "C" void kernel_launch(void* const* d_in, const int* in_sizes, int n_in,
                              void* d_out, int out_size, void* d_ws, size_t ws_size,
                              hipStream_t stream)
{
    // Guard: never touch memory past the provided workspace (a prior OOB
    // fault can wedge the whole container). Deterministic: ws_size is fixed
    // per harness run, so this branch behaves identically on every call.
    const size_t WS_NEED_FLOATS = 38658912;  // 154.6 MB
    if (ws_size < WS_NEED_FLOATS * sizeof(float)) return;

    const float* para  = (const float*)d_in[0];
    const float* q     = (const float*)d_in[1];
    const float* qwh   = (const float*)d_in[2];
    const float* stW1  = (const float*)d_in[3];
    const float* stb1  = (const float*)d_in[4];
    const float* stW2  = (const float*)d_in[5];
    const float* stb2  = (const float*)d_in[6];
    const float* mW1   = (const float*)d_in[7];
    const float* mb1   = (const float*)d_in[8];
    const float* mW2   = (const float*)d_in[9];
    const float* mb2   = (const float*)d_in[10];
    const float* pW1   = (const float*)d_in[11];
    const float* pb1   = (const float*)d_in[12];
    const float* pW2   = (const float*)d_in[13];
    const float* pb2   = (const float*)d_in[14];
    const float* simW1 = (const float*)d_in[15];
    const float* simb1 = (const float*)d_in[16];
    const float* simW2 = (const float*)d_in[17];
    const float* simb2 = (const float*)d_in[18];
    const float* hW1   = (const float*)d_in[19];
    const float* hb1   = (const float*)d_in[20];
    const float* hW2   = (const float*)d_in[21];
    const float* hb2   = (const float*)d_in[22];
    const int*   mpos  = (const int*)d_in[23];
    const int*   mid   = (const int*)d_in[24];
    const int*   ppos  = (const int*)d_in[25];
    const int*   pso   = (const int*)d_in[26];

    // ---- workspace layout (floats): peak ~38.7M floats = 154.6 MB ----
    float* ws     = (float*)d_ws;
    float* FEAT_S = ws;                    // 15,360,000: ent_mean -> sub_feat -> pair_emb (20000x768)
    float* OBJ    = FEAT_S + 15360000;     //  7,680,000: obj_feat chunk; later H256 (20000x256)
    float* ENTE   = OBJ    + 7680000;      //  7,680,000: ent_emb (10000x768)
    float* HID    = ENTE   + 7680000;      //  7,680,000: 10000x768 hidden (chunked)
    float* simb   = HID    + 7680000;      //     20,000
    float* probs  = simb   + 20000;        //     30,000 (3 x 10000)
    float* newe   = probs  + 30000;        //     10,000
    float* h1     = newe   + 10000;        //        768
    float* cq     = h1     + 768;          //        768
    float* ctx    = cq     + 768;          //        768
    float* W1s    = ctx    + 768;          //    196,608

    dim3 B256(256);
    const dim3 gEnt(79, 6);   // 10000x768 tiles
    const dim3 gEntH(79, 2);  // 10000x256
    const dim3 gChk(79, 6);   // 10000x768 per chunk

    // 1) entity mention means (10000 x 1536) -> FEAT_S
    k_entmean<<<NENT, 256, 0, stream>>>(para, mpos, mid, MMENT, FEAT_S);

    // 2) ent_emb: FEAT_S @ mW1 -> HID; HID @ mW2 -> ENTE
    gemm_k<0, 1><<<gEnt, B256, 0, stream>>>(FEAT_S, nullptr, nullptr, 0, 0, nullptr, nullptr,
                                            mW1, mb1, HID, NENT, D, 2 * D);
    gemm_k<0, 0><<<gEnt, B256, 0, stream>>>(HID, nullptr, nullptr, 0, 0, nullptr, nullptr,
                                            mW2, mb2, ENTE, NENT, D, D);

    // 3+4) per chunk: sub_feat -> FEAT_S chunk; obj_feat -> OBJ;
    //      pair_emb = mlp([s,o,o-s,s*o]) overwrites FEAT_S chunk
    for (int c = 0; c < NPAIR / CHUNK; ++c) {
        const int* pp = ppos + (size_t)c * CHUNK * 5;
        float* sdst = FEAT_S + (size_t)c * CHUNK * D;
        gemm_k<1, 1><<<gChk, B256, 0, stream>>>(nullptr, para, pp, 1, 2, nullptr, nullptr,
                                                mW1, mb1, HID, CHUNK, D, 2 * D);
        gemm_k<0, 0><<<gChk, B256, 0, stream>>>(HID, nullptr, nullptr, 0, 0, nullptr, nullptr,
                                                mW2, mb2, sdst, CHUNK, D, D);
        gemm_k<1, 1><<<gChk, B256, 0, stream>>>(nullptr, para, pp, 3, 4, nullptr, nullptr,
                                                mW1, mb1, HID, CHUNK, D, 2 * D);
        gemm_k<0, 0><<<gChk, B256, 0, stream>>>(HID, nullptr, nullptr, 0, 0, nullptr, nullptr,
                                                mW2, mb2, OBJ, CHUNK, D, D);
        gemm_k<2, 1><<<gChk, B256, 0, stream>>>(nullptr, nullptr, nullptr, 0, 0, sdst, OBJ,
                                                pW1, pb1, HID, CHUNK, D, 4 * D);
        gemm_k<0, 0><<<gChk, B256, 0, stream>>>(HID, nullptr, nullptr, 0, 0, nullptr, nullptr,
                                                pW2, pb2, sdst, CHUNK, D, D);
    }

    // 5) reasoning steps; H256 buffer (20000x256) lives in OBJ (now dead)
    float* H256 = OBJ;
    for (int t = 0; t < NSTEP; ++t) {
        k_vecmat<<<3, 256, 0, stream>>>(q, stW1 + (size_t)t * D * D, stb1 + t * D, h1, D, D, 1);
        k_vecmat<<<3, 256, 0, stream>>>(h1, stW2 + (size_t)t * D * D, stb2 + t * D, cq, D, D, 0);
        k_ctx<<<1, 256, 0, stream>>>(cq, qwh, ctx);
        k_scalew<<<768, 256, 0, stream>>>(ctx, simW1, W1s, D * 256);
        if (t == 0) {
            gemm_k<0, 1><<<gEntH, B256, 0, stream>>>(ENTE, nullptr, nullptr, 0, 0, nullptr,
                                                     nullptr, W1s, simb1, H256, NENT, 256, D);
            k_rowdot<0><<<NENT / 4, 256, 0, stream>>>(H256, simW2, simb2, NENT, simb,
                                                      nullptr, nullptr, nullptr);
            k_softmax<<<1, 256, 0, stream>>>(simb, probs, NENT);
        } else {
            gemm_k<0, 1><<<dim3(157, 2), B256, 0, stream>>>(FEAT_S, nullptr, nullptr, 0, 0,
                                                            nullptr, nullptr, W1s, simb1, H256,
                                                            NPAIR, 256, D);
            k_zero<<<40, 256, 0, stream>>>(newe, NENT);
            k_rowdot<1><<<NPAIR / 4, 256, 0, stream>>>(H256, simW2, simb2, NPAIR, nullptr,
                                                       probs + (t - 1) * NENT, pso, newe);
            k_clampstore<<<40, 256, 0, stream>>>(newe, probs + t * NENT, NENT);
        }
    }

    // 6) hop attention + final mix
    k_vecmat<<<1, 256, 0, stream>>>(q, hW1, hb1, h1, D, 256, 1);
    k_vecmat<<<1, 256, 0, stream>>>(h1, hW2, hb2, cq, 256, 3, 0);
    k_final<<<40, 256, 0, stream>>>(probs, cq, (float*)d_out, NENT);
}

// Round 6
// 4851.864 us; speedup vs baseline: 1.5531x; 1.5531x over previous
//
#include <hip/hip_runtime.h>
#include <math.h>

// ---------------------------------------------------------------------------
// Sizes (fixed by the problem)
// ---------------------------------------------------------------------------
#define D 768
#define NPARA 32
#define LPARA 512
#define LQ 32
#define NENT 10000
#define MMENT 30000
#define NPAIR 20000
#define NSTEP 3
#define CHUNK 10000

using bf16x8 = __attribute__((ext_vector_type(8))) short;   // 8 bf16 in 4 VGPRs
using f32x4  = __attribute__((ext_vector_type(4))) float;

__device__ __forceinline__ float geluf(float x) {
    return 0.5f * x * (1.0f + erff(x * 0.70710678118654752f));
}
__device__ __forceinline__ float bf2f(ushort h) {
    union { unsigned u; float f; } v; v.u = ((unsigned)h) << 16; return v.f;
}
__device__ __forceinline__ ushort bfhi(float x) {
    union { float f; unsigned u; } v; v.f = x; return (ushort)(v.u >> 16);
}
// truncation split: x ~= hi + lo, |err| <~ 2^-16 |x|
__device__ __forceinline__ void bfsplit(float x, ushort& h, ushort& l) {
    h = bfhi(x);
    l = bfhi(x - bf2f(h));
}

// ---------------------------------------------------------------------------
// Split-bf16 MFMA GEMM: C[M,N] = act(A@W + bias), 3-term hi/lo split.
// A source per MODE: 0 = hi/lo bf16 planes [M][K]
//                    1 = gather from para fp32 (pair_pos cols c1/c2), K=1536
//                    2 = synth [s,o,o-s,s*o] from S/O hi-lo planes, K=3072
// B: pre-transposed weight planes WT[N][K] (hi/lo bf16).
// OUTP: 0 = fp32 C; 1 = hi/lo bf16 planes Ch/Cl.
// Tile 128x128xBK64; 4 waves of 64x64; XOR-swizzled LDS (conflict-free b128).
// ---------------------------------------------------------------------------
#define BM 128
#define BN 128

__device__ __forceinline__ int ldso(int row, int kb) {   // ushort index in a plane
    return row * 64 + (((kb) ^ ((row & 7) << 4)) >> 1);
}

template <int MODE, int ACT, int OUTP>
__global__ __launch_bounds__(256) void gemm_m(
    const ushort* __restrict__ Ah, const ushort* __restrict__ Al,
    const float* __restrict__ para, const int* __restrict__ ppos, int c1, int c2,
    const ushort* __restrict__ Sh, const ushort* __restrict__ Sl,
    const ushort* __restrict__ Oh, const ushort* __restrict__ Ol,
    const ushort* __restrict__ Bh, const ushort* __restrict__ Bl,
    const float* __restrict__ bias,
    float* __restrict__ Cf, ushort* __restrict__ Ch, ushort* __restrict__ Cl,
    int M, int N, int K)
{
    __shared__ ushort sAh[BM * 64], sAl[BM * 64], sBh[BN * 64], sBl[BN * 64];

    const int tid = threadIdx.x;
    const int m0 = blockIdx.x * BM;
    const int n0 = blockIdx.y * BN;

    const int lane = tid & 63;
    const int wv = tid >> 6;
    const int wr = (wv >> 1) * 64;   // wave row offset in tile
    const int wc = (wv & 1) * 64;    // wave col offset
    const int ln = lane & 15;
    const int kg = lane >> 4;

    f32x4 acc[4][4];
#pragma unroll
    for (int i = 0; i < 4; ++i)
#pragma unroll
        for (int j = 0; j < 4; ++j)
#pragma unroll
            for (int e = 0; e < 4; ++e) acc[i][j][e] = 0.0f;

    const int srow = tid & 127;       // staging row
    const int shalf = tid >> 7;       // 0/1: which 32-col half

    for (int kt = 0; kt < K; kt += 64) {
        // ---------------- stage A tile (128 x 64, hi+lo) ----------------
        {
            const int gm = m0 + srow;
            const bool ok = gm < M;
            if (MODE == 0) {
                const ushort* gh = Ah + (size_t)gm * K + kt;
                const ushort* gl = Al + (size_t)gm * K + kt;
#pragma unroll
                for (int j = 0; j < 4; ++j) {
                    int kc = shalf * 32 + j * 8;
                    bf16x8 vh, vl;
                    if (ok) {
                        vh = *(const bf16x8*)(gh + kc);
                        vl = *(const bf16x8*)(gl + kc);
                    } else {
#pragma unroll
                        for (int z = 0; z < 8; ++z) { vh[z] = 0; vl[z] = 0; }
                    }
                    int o = ldso(srow, kc * 2);
                    *(bf16x8*)&sAh[o] = vh;
                    *(bf16x8*)&sAl[o] = vl;
                }
            } else if (MODE == 1) {
                int gbase = 0;
                if (ok) {
                    int p = ppos[gm * 5];
                    int t = (kt < D) ? ppos[gm * 5 + c1] : ppos[gm * 5 + c2];
                    gbase = (p * LPARA + t) * D + ((kt < D) ? kt : kt - D);
                }
#pragma unroll
                for (int j = 0; j < 8; ++j) {
                    int kc = shalf * 32 + j * 4;
                    float4 v = make_float4(0.f, 0.f, 0.f, 0.f);
                    if (ok) v = *(const float4*)(para + gbase + kc);
                    ushort4 h, l;
                    bfsplit(v.x, h.x, l.x); bfsplit(v.y, h.y, l.y);
                    bfsplit(v.z, h.z, l.z); bfsplit(v.w, h.w, l.w);
                    int o = ldso(srow, kc * 2);
                    *(ushort4*)&sAh[o] = h;
                    *(ushort4*)&sAl[o] = l;
                }
            } else {  // MODE 2: synth sections of [s, o, o-s, s*o]
                const int sec = kt / D;
                const int r0 = kt - sec * D;
                const size_t rb = (size_t)gm * D + r0;
#pragma unroll
                for (int j = 0; j < 8; ++j) {
                    int kc = shalf * 32 + j * 4;
                    ushort4 h, l;
                    if (ok) {
                        ushort4 a = *(const ushort4*)(Sh + rb + kc);
                        ushort4 b = *(const ushort4*)(Sl + rb + kc);
                        ushort4 c = *(const ushort4*)(Oh + rb + kc);
                        ushort4 d = *(const ushort4*)(Ol + rb + kc);
                        float sv[4] = { bf2f(a.x) + bf2f(b.x), bf2f(a.y) + bf2f(b.y),
                                        bf2f(a.z) + bf2f(b.z), bf2f(a.w) + bf2f(b.w) };
                        float ov[4] = { bf2f(c.x) + bf2f(d.x), bf2f(c.y) + bf2f(d.y),
                                        bf2f(c.z) + bf2f(d.z), bf2f(c.w) + bf2f(d.w) };
                        float val[4];
#pragma unroll
                        for (int e = 0; e < 4; ++e)
                            val[e] = (sec == 0) ? sv[e] : (sec == 1) ? ov[e]
                                   : (sec == 2) ? (ov[e] - sv[e]) : (sv[e] * ov[e]);
                        bfsplit(val[0], h.x, l.x); bfsplit(val[1], h.y, l.y);
                        bfsplit(val[2], h.z, l.z); bfsplit(val[3], h.w, l.w);
                    } else {
                        h.x = h.y = h.z = h.w = 0; l = h;
                    }
                    int o = ldso(srow, kc * 2);
                    *(ushort4*)&sAh[o] = h;
                    *(ushort4*)&sAl[o] = l;
                }
            }
        }
        // ---------------- stage B tile (128 n-rows x 64 k, hi+lo) ----------------
        {
            const int gn = n0 + srow;          // N is a multiple of 128
            const ushort* gh = Bh + (size_t)gn * K + kt;
            const ushort* gl = Bl + (size_t)gn * K + kt;
#pragma unroll
            for (int j = 0; j < 4; ++j) {
                int kc = shalf * 32 + j * 8;
                bf16x8 vh = *(const bf16x8*)(gh + kc);
                bf16x8 vl = *(const bf16x8*)(gl + kc);
                int o = ldso(srow, kc * 2);
                *(bf16x8*)&sBh[o] = vh;
                *(bf16x8*)&sBl[o] = vl;
            }
        }
        __syncthreads();

        // ---------------- MFMA over the 64-k tile (2 steps of 32) ----------------
#pragma unroll
        for (int ks = 0; ks < 2; ++ks) {
            bf16x8 fah[4], fal[4], fbh[4], fbl[4];
#pragma unroll
            for (int mi = 0; mi < 4; ++mi) {
                int r = wr + mi * 16 + ln;
                int o = ldso(r, ks * 64 + kg * 16);
                fah[mi] = *(const bf16x8*)&sAh[o];
                fal[mi] = *(const bf16x8*)&sAl[o];
            }
#pragma unroll
            for (int ni = 0; ni < 4; ++ni) {
                int r = wc + ni * 16 + ln;
                int o = ldso(r, ks * 64 + kg * 16);
                fbh[ni] = *(const bf16x8*)&sBh[o];
                fbl[ni] = *(const bf16x8*)&sBl[o];
            }
#pragma unroll
            for (int mi = 0; mi < 4; ++mi)
#pragma unroll
                for (int ni = 0; ni < 4; ++ni) {
                    acc[mi][ni] = __builtin_amdgcn_mfma_f32_16x16x32_bf16(
                        fah[mi], fbh[ni], acc[mi][ni], 0, 0, 0);
                    acc[mi][ni] = __builtin_amdgcn_mfma_f32_16x16x32_bf16(
                        fah[mi], fbl[ni], acc[mi][ni], 0, 0, 0);
                    acc[mi][ni] = __builtin_amdgcn_mfma_f32_16x16x32_bf16(
                        fal[mi], fbh[ni], acc[mi][ni], 0, 0, 0);
                }
        }
        __syncthreads();
    }

    // ---------------- epilogue: C row = (lane>>4)*4+reg, col = lane&15 ----------------
#pragma unroll
    for (int mi = 0; mi < 4; ++mi)
#pragma unroll
        for (int ni = 0; ni < 4; ++ni) {
            int col = n0 + wc + ni * 16 + ln;
            f32x4 a = acc[mi][ni];
#pragma unroll
            for (int j = 0; j < 4; ++j) {
                int row = m0 + wr + mi * 16 + kg * 4 + j;
                if (row < M) {
                    float v = a[j] + bias[col];
                    if (ACT == 1) v = geluf(v);
                    if (OUTP == 0) {
                        Cf[(size_t)row * N + col] = v;
                    } else {
                        ushort h, l;
                        bfsplit(v, h, l);
                        Ch[(size_t)row * N + col] = h;
                        Cl[(size_t)row * N + col] = l;
                    }
                }
            }
        }
}

// ---------------------------------------------------------------------------
// Weight transpose + split: W[K][N] fp32 -> WT[N][K] hi/lo bf16 planes
// ---------------------------------------------------------------------------
__global__ __launch_bounds__(256) void k_wt(const float* __restrict__ W,
                                            ushort* __restrict__ WTh,
                                            ushort* __restrict__ WTl, int K, int N)
{
    __shared__ float t[32][33];
    const int k0 = blockIdx.x * 32, n0 = blockIdx.y * 32;
    const int c = threadIdx.x & 31, r8 = threadIdx.x >> 5;
#pragma unroll
    for (int i = 0; i < 4; ++i) {
        int r = r8 + i * 8;
        t[r][c] = W[(size_t)(k0 + r) * N + n0 + c];
    }
    __syncthreads();
#pragma unroll
    for (int i = 0; i < 4; ++i) {
        int r = r8 + i * 8;
        float v = t[c][r];
        ushort h, l;
        bfsplit(v, h, l);
        WTh[(size_t)(n0 + r) * K + k0 + c] = h;
        WTl[(size_t)(n0 + r) * K + k0 + c] = l;
    }
}

// ---------------------------------------------------------------------------
// Per-entity mention mean -> hi/lo bf16 planes [NENT][1536]
// ---------------------------------------------------------------------------
__global__ __launch_bounds__(256) void k_entmean(
    const float* __restrict__ para, const int* __restrict__ mpos,
    const int* __restrict__ mid, int M, ushort* __restrict__ oh, ushort* __restrict__ ol)
{
    __shared__ int sb[2];
    const int e = blockIdx.x;
    if (threadIdx.x < 2) {
        int target = e + threadIdx.x;
        int lo = 0, hi = M;
        while (lo < hi) {
            int md = (lo + hi) >> 1;
            if (mid[md] < target) lo = md + 1; else hi = md;
        }
        sb[threadIdx.x] = lo;
    }
    __syncthreads();
    const int lo = sb[0], hi = sb[1];
    const int tid = threadIdx.x;
    float a0 = 0, a1 = 0, a2 = 0, b0 = 0, b1 = 0, b2 = 0;
    for (int m = lo; m < hi; ++m) {
        int p = mpos[m * 3], t1 = mpos[m * 3 + 1], t2 = mpos[m * 3 + 2];
        const float* L = para + (size_t)(p * LPARA + t1) * D;
        const float* R = para + (size_t)(p * LPARA + t2) * D;
        a0 += L[tid]; a1 += L[tid + 256]; a2 += L[tid + 512];
        b0 += R[tid]; b1 += R[tid + 256]; b2 += R[tid + 512];
    }
    const float inv = (hi > lo) ? 1.0f / (float)(hi - lo) : 0.0f;
    size_t base = (size_t)e * (2 * D);
    float vals[6] = { a0 * inv, a1 * inv, a2 * inv, b0 * inv, b1 * inv, b2 * inv };
    int offs[6] = { tid, tid + 256, tid + 512, D + tid, D + tid + 256, D + tid + 512 };
#pragma unroll
    for (int i = 0; i < 6; ++i) {
        ushort h, l;
        bfsplit(vals[i], h, l);
        oh[base + offs[i]] = h;
        ol[base + offs[i]] = l;
    }
}

// out[j] = act(sum_k x[k]*W[k*N+j] + b[j])
__global__ void k_vecmat(const float* __restrict__ x, const float* __restrict__ W,
                         const float* __restrict__ b, float* __restrict__ out,
                         int K, int N, int act)
{
    int j = blockIdx.x * blockDim.x + threadIdx.x;
    if (j >= N) return;
    float s = 0.0f;
    for (int k = 0; k < K; ++k) s = fmaf(x[k], W[(size_t)k * N + j], s);
    s += b[j];
    if (act) s = geluf(s);
    out[j] = s;
}

// ctx = softmax(cq . qwh_l) @ qwh + cq
__global__ void k_ctx(const float* __restrict__ cq, const float* __restrict__ qwh,
                      float* __restrict__ ctx)
{
    __shared__ float red[256];
    __shared__ float dist[LQ];
    const int tid = threadIdx.x;
    const int l = tid >> 3, part = tid & 7;
    float s = 0.0f;
    for (int d = part; d < D; d += 8) s += cq[d] * qwh[l * D + d];
    red[tid] = s;
    __syncthreads();
    if (part == 0) {
        float v = 0;
        for (int i = 0; i < 8; ++i) v += red[l * 8 + i];
        dist[l] = v;
    }
    __syncthreads();
    if (tid == 0) {
        float mx = -1e30f;
        for (int i = 0; i < LQ; ++i) mx = fmaxf(mx, dist[i]);
        float sm = 0;
        for (int i = 0; i < LQ; ++i) { float e = expf(dist[i] - mx); dist[i] = e; sm += e; }
        float inv = 1.0f / sm;
        for (int i = 0; i < LQ; ++i) dist[i] *= inv;
    }
    __syncthreads();
    for (int d = tid; d < D; d += 256) {
        float v = 0;
#pragma unroll
        for (int l2 = 0; l2 < LQ; ++l2) v += dist[l2] * qwh[l2 * D + d];
        ctx[d] = v + cq[d];
    }
}

// W1s[k,j] = ctx[k] * sW1[k,j]
__global__ void k_scalew(const float* __restrict__ ctx, const float* __restrict__ w1,
                         float* __restrict__ o, int n)
{
    int i = blockIdx.x * 256 + threadIdx.x;
    if (i < n) o[i] = ctx[i >> 8] * w1[i];
}

// sim[r] = sum_j H[r,j]*w2[j] + sb2;  PAIRMODE: sigmoid, gather, atomic scatter
template <int PAIRMODE>
__global__ void k_rowdot(const float* __restrict__ H, const float* __restrict__ w2,
                         const float* __restrict__ sb2, int Nr,
                         float* __restrict__ simout,
                         const float* __restrict__ laste, const int* __restrict__ so,
                         float* __restrict__ newe)
{
    int r = blockIdx.x * 4 + (threadIdx.x >> 6);
    int lane = threadIdx.x & 63;
    if (r >= Nr) return;
    float s = 0.0f;
#pragma unroll
    for (int i = 0; i < 4; ++i)
        s += H[(size_t)r * 256 + lane + i * 64] * w2[lane + i * 64];
    for (int off = 32; off > 0; off >>= 1) s += __shfl_down(s, off, 64);
    if (lane == 0) {
        s += sb2[0];
        if (PAIRMODE == 0) {
            simout[r] = s;
        } else {
            float p = 1.0f / (1.0f + expf(-s));
            float v = laste[so[r * 2]] * p;
            atomicAdd(&newe[so[r * 2 + 1]], v);
        }
    }
}

__global__ void k_softmax(const float* __restrict__ sim, float* __restrict__ outp, int n)
{
    __shared__ float red[256];
    __shared__ float s_mx, s_sum;
    const int tid = threadIdx.x;
    float mx = -1e30f;
    for (int i = tid; i < n; i += 256) mx = fmaxf(mx, sim[i]);
    red[tid] = mx; __syncthreads();
    for (int off = 128; off > 0; off >>= 1) {
        if (tid < off) red[tid] = fmaxf(red[tid], red[tid + off]);
        __syncthreads();
    }
    if (tid == 0) s_mx = red[0];
    __syncthreads();
    const float mxv = s_mx;
    float sum = 0;
    for (int i = tid; i < n; i += 256) sum += expf(sim[i] - mxv);
    red[tid] = sum; __syncthreads();
    for (int off = 128; off > 0; off >>= 1) {
        if (tid < off) red[tid] += red[tid + off];
        __syncthreads();
    }
    if (tid == 0) s_sum = red[0];
    __syncthreads();
    const float inv = 1.0f / s_sum;
    for (int i = tid; i < n; i += 256) {
        float v = expf(sim[i] - mxv) * inv;
        outp[i] = v / fmaxf(v, 1.0f);
    }
}

__global__ void k_zero(float* p, int n)
{
    int i = blockIdx.x * blockDim.x + threadIdx.x;
    if (i < n) p[i] = 0.0f;
}

__global__ void k_clampstore(const float* __restrict__ ne, float* __restrict__ outp, int n)
{
    int i = blockIdx.x * blockDim.x + threadIdx.x;
    if (i < n) { float v = ne[i]; outp[i] = v / fmaxf(v, 1.0f); }
}

__global__ void k_final(const float* __restrict__ probs, const float* __restrict__ hlog,
                        float* __restrict__ out, int n)
{
    int i = blockIdx.x * blockDim.x + threadIdx.x;
    if (i >= n) return;
    float l0 = hlog[0], l1 = hlog[1], l2 = hlog[2];
    float m = fmaxf(l0, fmaxf(l1, l2));
    float e0 = expf(l0 - m), e1 = expf(l1 - m), e2 = expf(l2 - m);
    float inv = 1.0f / (e0 + e1 + e2);
    out[i] = (e0 * probs[i] + e1 * probs[n + i] + e2 * probs[2 * n + i]) * inv;
}

// ---------------------------------------------------------------------------
extern "C" void kernel_launch(void* const* d_in, const int* in_sizes, int n_in,
                              void* d_out, int out_size, void* d_ws, size_t ws_size,
                              hipStream_t stream)
{
    const size_t WS_NEED = 145149312;  // 138.4 MiB (see layout below)
    if (ws_size < WS_NEED) return;

    const float* para  = (const float*)d_in[0];
    const float* q     = (const float*)d_in[1];
    const float* qwh   = (const float*)d_in[2];
    const float* stW1  = (const float*)d_in[3];
    const float* stb1  = (const float*)d_in[4];
    const float* stW2  = (const float*)d_in[5];
    const float* stb2  = (const float*)d_in[6];
    const float* mW1   = (const float*)d_in[7];
    const float* mb1   = (const float*)d_in[8];
    const float* mW2   = (const float*)d_in[9];
    const float* mb2   = (const float*)d_in[10];
    const float* pW1   = (const float*)d_in[11];
    const float* pb1   = (const float*)d_in[12];
    const float* pW2   = (const float*)d_in[13];
    const float* pb2   = (const float*)d_in[14];
    const float* simW1 = (const float*)d_in[15];
    const float* simb1 = (const float*)d_in[16];
    const float* simW2 = (const float*)d_in[17];
    const float* simb2 = (const float*)d_in[18];
    const float* hW1   = (const float*)d_in[19];
    const float* hb1   = (const float*)d_in[20];
    const float* hW2   = (const float*)d_in[21];
    const float* hb2   = (const float*)d_in[22];
    const int*   mpos  = (const int*)d_in[23];
    const int*   mid   = (const int*)d_in[24];
    const int*   ppos  = (const int*)d_in[25];
    const int*   pso   = (const int*)d_in[26];

    // ---- workspace layout ----
    ushort* P1h  = (ushort*)d_ws;          // 15,360,000  (EM 10000x1536 -> SUB/pair_emb 20000x768)
    ushort* P1l  = P1h  + 15360000;
    ushort* HIDh = P1l  + 15360000;        //  7,680,000  (hidden 10000x768; later H256 fp32 overlay)
    ushort* HIDl = HIDh + 7680000;
    ushort* Eh   = HIDl + 7680000;         //  7,680,000  (ent_emb; later obj_feat chunk)
    ushort* El   = Eh   + 7680000;
    ushort* mW1Th = El    + 7680000;       // 1,179,648 each
    ushort* mW1Tl = mW1Th + 1179648;
    ushort* mW2Th = mW1Tl + 1179648;       //   589,824
    ushort* mW2Tl = mW2Th + 589824;
    ushort* pW1Th = mW2Tl + 589824;        // 2,359,296
    ushort* pW1Tl = pW1Th + 2359296;
    ushort* pW2Th = pW1Tl + 2359296;       //   589,824
    ushort* pW2Tl = pW2Th + 589824;
    ushort* W1sTh0 = pW2Tl + 589824;       //   196,608 each (3 steps h + 3 steps l)
    ushort* W1sTl0 = W1sTh0 + 3 * 196608;
    float*  W1s   = (float*)(W1sTl0 + 3 * 196608);  // 196,608 fp32
    float*  simb  = W1s  + 196608;         // 20,000
    float*  probs = simb + 20000;          // 30,000
    float*  newe  = probs + 30000;         // 10,000
    float*  h1    = newe + 10000;          // 768
    float*  cq    = h1   + 768;            // 768
    float*  ctx   = cq   + 768;            // 768
    float*  H256  = (float*)HIDh;          // overlay: 20000x256 fp32 = 20.5MB <= 30.7MB

    dim3 B256(256);
    const dim3 g10_768(79, 6), g10_256(79, 2), g20_256(157, 2);
    const ushort* np = nullptr;

    // 0) weight transpose+split
    k_wt<<<dim3(48, 24), B256, 0, stream>>>(mW1, mW1Th, mW1Tl, 2 * D, D);
    k_wt<<<dim3(24, 24), B256, 0, stream>>>(mW2, mW2Th, mW2Tl, D, D);
    k_wt<<<dim3(96, 24), B256, 0, stream>>>(pW1, pW1Th, pW1Tl, 4 * D, D);
    k_wt<<<dim3(24, 24), B256, 0, stream>>>(pW2, pW2Th, pW2Tl, D, D);

    // 1) per-step ctx -> scaled+transposed sim weight (depends only on q inputs)
    for (int t = 0; t < NSTEP; ++t) {
        k_vecmat<<<3, 256, 0, stream>>>(q, stW1 + (size_t)t * D * D, stb1 + t * D, h1, D, D, 1);
        k_vecmat<<<3, 256, 0, stream>>>(h1, stW2 + (size_t)t * D * D, stb2 + t * D, cq, D, D, 0);
        k_ctx<<<1, 256, 0, stream>>>(cq, qwh, ctx);
        k_scalew<<<768, 256, 0, stream>>>(ctx, simW1, W1s, D * 256);
        k_wt<<<dim3(24, 8), B256, 0, stream>>>(W1s, W1sTh0 + t * 196608, W1sTl0 + t * 196608,
                                               D, 256);
    }

    // 2) entity mention means -> P1 planes (10000 x 1536)
    k_entmean<<<NENT, 256, 0, stream>>>(para, mpos, mid, MMENT, P1h, P1l);

    // 3) ent_emb: gelu(EM@mW1) -> HID; HID@mW2 -> E
    gemm_m<0, 1, 1><<<g10_768, B256, 0, stream>>>(P1h, P1l, nullptr, nullptr, 0, 0,
        np, np, np, np, mW1Th, mW1Tl, mb1, nullptr, HIDh, HIDl, NENT, D, 2 * D);
    gemm_m<0, 0, 1><<<g10_768, B256, 0, stream>>>(HIDh, HIDl, nullptr, nullptr, 0, 0,
        np, np, np, np, mW2Th, mW2Tl, mb2, nullptr, Eh, El, NENT, D, D);

    // 4) step 0: sim on entities -> probs[0]   (E dead afterwards)
    gemm_m<0, 1, 0><<<g10_256, B256, 0, stream>>>(Eh, El, nullptr, nullptr, 0, 0,
        np, np, np, np, W1sTh0, W1sTl0, simb1, H256, nullptr, nullptr, NENT, 256, D);
    k_rowdot<0><<<NENT / 4, 256, 0, stream>>>(H256, simW2, simb2, NENT, simb,
                                              nullptr, nullptr, nullptr);
    k_softmax<<<1, 256, 0, stream>>>(simb, probs, NENT);

    // 5) pair pipeline, chunked (CHUNK=10000); SUB stages through the P1 slot,
    //    OBJ through the E slot, pair_emb overwrites the SUB chunk.
    for (int c = 0; c < NPAIR / CHUNK; ++c) {
        const int* pp = ppos + (size_t)c * CHUNK * 5;
        ushort* sdh = P1h + (size_t)c * CHUNK * D;
        ushort* sdl = P1l + (size_t)c * CHUNK * D;
        gemm_m<1, 1, 1><<<g10_768, B256, 0, stream>>>(np, np, para, pp, 1, 2,
            np, np, np, np, mW1Th, mW1Tl, mb1, nullptr, HIDh, HIDl, CHUNK, D, 2 * D);
        gemm_m<0, 0, 1><<<g10_768, B256, 0, stream>>>(HIDh, HIDl, nullptr, nullptr, 0, 0,
            np, np, np, np, mW2Th, mW2Tl, mb2, nullptr, sdh, sdl, CHUNK, D, D);
        gemm_m<1, 1, 1><<<g10_768, B256, 0, stream>>>(np, np, para, pp, 3, 4,
            np, np, np, np, mW1Th, mW1Tl, mb1, nullptr, HIDh, HIDl, CHUNK, D, 2 * D);
        gemm_m<0, 0, 1><<<g10_768, B256, 0, stream>>>(HIDh, HIDl, nullptr, nullptr, 0, 0,
            np, np, np, np, mW2Th, mW2Tl, mb2, nullptr, Eh, El, CHUNK, D, D);
        gemm_m<2, 1, 1><<<g10_768, B256, 0, stream>>>(np, np, nullptr, nullptr, 0, 0,
            sdh, sdl, Eh, El, pW1Th, pW1Tl, pb1, nullptr, HIDh, HIDl, CHUNK, D, 4 * D);
        gemm_m<0, 0, 1><<<g10_768, B256, 0, stream>>>(HIDh, HIDl, nullptr, nullptr, 0, 0,
            np, np, np, np, pW2Th, pW2Tl, pb2, nullptr, sdh, sdl, CHUNK, D, D);
    }

    // 6) steps 1,2: sim on pairs, scatter-propagate probabilities
    for (int t = 1; t < NSTEP; ++t) {
        gemm_m<0, 1, 0><<<g20_256, B256, 0, stream>>>(P1h, P1l, nullptr, nullptr, 0, 0,
            np, np, np, np, W1sTh0 + t * 196608, W1sTl0 + t * 196608, simb1,
            H256, nullptr, nullptr, NPAIR, 256, D);
        k_zero<<<40, 256, 0, stream>>>(newe, NENT);
        k_rowdot<1><<<NPAIR / 4, 256, 0, stream>>>(H256, simW2, simb2, NPAIR, nullptr,
                                                   probs + (t - 1) * NENT, pso, newe);
        k_clampstore<<<40, 256, 0, stream>>>(newe, probs + t * NENT, NENT);
    }

    // 7) hop attention + final mix
    k_vecmat<<<1, 256, 0, stream>>>(q, hW1, hb1, h1, D, 256, 1);
    k_vecmat<<<1, 256, 0, stream>>>(h1, hW2, hb2, cq, 256, 3, 0);
    k_final<<<40, 256, 0, stream>>>(probs, cq, (float*)d_out, NENT);
}

// Round 7
// 3601.039 us; speedup vs baseline: 2.0926x; 1.3474x over previous
//
#include <hip/hip_runtime.h>
#include <math.h>

// ---------------------------------------------------------------------------
#define D 768
#define NPARA 32
#define LPARA 512
#define LQ 32
#define NENT 10000
#define MMENT 30000
#define NPAIR 20000
#define NSTEP 3
#define CHUNK 10000

using bf16x8 = __attribute__((ext_vector_type(8))) short;
using f32x4  = __attribute__((ext_vector_type(4))) float;

__device__ __forceinline__ float geluf(float x) {
    return 0.5f * x * (1.0f + erff(x * 0.70710678118654752f));
}
__device__ __forceinline__ float bf2f(ushort h) {
    union { unsigned u; float f; } v; v.u = ((unsigned)h) << 16; return v.f;
}
__device__ __forceinline__ ushort bfhi(float x) {
    union { float f; unsigned u; } v; v.f = x; return (ushort)(v.u >> 16);
}
__device__ __forceinline__ void bfsplit(float x, ushort& h, ushort& l) {
    h = bfhi(x);
    l = bfhi(x - bf2f(h));
}

// ---------------------------------------------------------------------------
// Split-bf16 MFMA GEMM with band-major XCD swizzle.
// MODE 0: A = hi/lo bf16 planes [M][K]
// MODE 1: A row r = concat(para[p,t1,:], para[p,t2,:]) fp32 gather, K=1536
// MODE 2: A row r, sections {S, O, S*O} from feat planes, K=2304 (folded W1)
// B: pre-transposed weight planes WT[N][K]. OUTP 0: fp32 C; 1: hi/lo planes.
// ---------------------------------------------------------------------------
#define BM 128
#define BN 128

__device__ __forceinline__ int ldso(int row, int kb) {
    return row * 64 + (((kb) ^ ((row & 7) << 4)) >> 1);
}

template <int MODE, int ACT, int OUTP>
__global__ __launch_bounds__(256) void gemm_m(
    const ushort* __restrict__ Ah, const ushort* __restrict__ Al,
    const float* __restrict__ para, const int* __restrict__ ppos, int c1, int c2,
    const ushort* __restrict__ Sh, const ushort* __restrict__ Sl,
    const ushort* __restrict__ Oh, const ushort* __restrict__ Ol,
    const ushort* __restrict__ Bh, const ushort* __restrict__ Bl,
    const float* __restrict__ bias,
    float* __restrict__ Cf, ushort* __restrict__ Ch, ushort* __restrict__ Cl,
    int M, int N, int K, int nby)
{
    __shared__ ushort sAh[BM * 64], sAl[BM * 64], sBh[BN * 64], sBl[BN * 64];

    // band-major bijective XCD swizzle (m204): contiguous wgid range per XCD;
    // wgid decodes col-fastest so one A-band's N-tiles share an XCD's L2.
    const int nwg = gridDim.x;
    const int q = nwg >> 3, r = nwg & 7;
    const int xcd = blockIdx.x & 7, idx = blockIdx.x >> 3;
    const int wgid = (xcd < r) ? xcd * (q + 1) + idx
                               : r * (q + 1) + (xcd - r) * q + idx;
    const int m0 = (wgid / nby) * BM;
    const int n0 = (wgid % nby) * BN;

    const int tid = threadIdx.x;
    const int lane = tid & 63;
    const int wv = tid >> 6;
    const int wr = (wv >> 1) * 64;
    const int wc = (wv & 1) * 64;
    const int ln = lane & 15;
    const int kg = lane >> 4;

    f32x4 acc[4][4];
#pragma unroll
    for (int i = 0; i < 4; ++i)
#pragma unroll
        for (int j = 0; j < 4; ++j)
#pragma unroll
            for (int e = 0; e < 4; ++e) acc[i][j][e] = 0.0f;

    const int srow = tid & 127;
    const int shalf = tid >> 7;

    for (int kt = 0; kt < K; kt += 64) {
        // ---------------- stage A tile (128 x 64, hi+lo) ----------------
        {
            const int gm = m0 + srow;
            const bool ok = gm < M;
            if (MODE == 0) {
                const ushort* gh = Ah + (size_t)gm * K + kt;
                const ushort* gl = Al + (size_t)gm * K + kt;
#pragma unroll
                for (int j = 0; j < 4; ++j) {
                    int kc = shalf * 32 + j * 8;
                    bf16x8 vh, vl;
                    if (ok) {
                        vh = *(const bf16x8*)(gh + kc);
                        vl = *(const bf16x8*)(gl + kc);
                    } else {
#pragma unroll
                        for (int z = 0; z < 8; ++z) { vh[z] = 0; vl[z] = 0; }
                    }
                    int o = ldso(srow, kc * 2);
                    *(bf16x8*)&sAh[o] = vh;
                    *(bf16x8*)&sAl[o] = vl;
                }
            } else if (MODE == 1) {
                int gbase = 0;
                if (ok) {
                    int p = ppos[gm * 5];
                    int t = (kt < D) ? ppos[gm * 5 + c1] : ppos[gm * 5 + c2];
                    gbase = (p * LPARA + t) * D + ((kt < D) ? kt : kt - D);
                }
#pragma unroll
                for (int j = 0; j < 8; ++j) {
                    int kc = shalf * 32 + j * 4;
                    float4 v = make_float4(0.f, 0.f, 0.f, 0.f);
                    if (ok) v = *(const float4*)(para + gbase + kc);
                    ushort4 h, l;
                    bfsplit(v.x, h.x, l.x); bfsplit(v.y, h.y, l.y);
                    bfsplit(v.z, h.z, l.z); bfsplit(v.w, h.w, l.w);
                    int o = ldso(srow, kc * 2);
                    *(ushort4*)&sAh[o] = h;
                    *(ushort4*)&sAl[o] = l;
                }
            } else {  // MODE 2: sections {S, O, S*O} (folded pair W1), K=2304
                const int sec = kt / D;
                const int r0 = kt - sec * D;
                const size_t rb = (size_t)gm * D + r0;
#pragma unroll
                for (int j = 0; j < 8; ++j) {
                    int kc = shalf * 32 + j * 4;
                    ushort4 h, l;
                    if (ok) {
                        float val[4];
                        if (sec == 0) {
                            ushort4 a = *(const ushort4*)(Sh + rb + kc);
                            ushort4 b = *(const ushort4*)(Sl + rb + kc);
                            val[0] = bf2f(a.x) + bf2f(b.x); val[1] = bf2f(a.y) + bf2f(b.y);
                            val[2] = bf2f(a.z) + bf2f(b.z); val[3] = bf2f(a.w) + bf2f(b.w);
                        } else if (sec == 1) {
                            ushort4 c = *(const ushort4*)(Oh + rb + kc);
                            ushort4 d = *(const ushort4*)(Ol + rb + kc);
                            val[0] = bf2f(c.x) + bf2f(d.x); val[1] = bf2f(c.y) + bf2f(d.y);
                            val[2] = bf2f(c.z) + bf2f(d.z); val[3] = bf2f(c.w) + bf2f(d.w);
                        } else {
                            ushort4 a = *(const ushort4*)(Sh + rb + kc);
                            ushort4 b = *(const ushort4*)(Sl + rb + kc);
                            ushort4 c = *(const ushort4*)(Oh + rb + kc);
                            ushort4 d = *(const ushort4*)(Ol + rb + kc);
                            val[0] = (bf2f(a.x) + bf2f(b.x)) * (bf2f(c.x) + bf2f(d.x));
                            val[1] = (bf2f(a.y) + bf2f(b.y)) * (bf2f(c.y) + bf2f(d.y));
                            val[2] = (bf2f(a.z) + bf2f(b.z)) * (bf2f(c.z) + bf2f(d.z));
                            val[3] = (bf2f(a.w) + bf2f(b.w)) * (bf2f(c.w) + bf2f(d.w));
                        }
                        bfsplit(val[0], h.x, l.x); bfsplit(val[1], h.y, l.y);
                        bfsplit(val[2], h.z, l.z); bfsplit(val[3], h.w, l.w);
                    } else {
                        h.x = h.y = h.z = h.w = 0; l = h;
                    }
                    int o = ldso(srow, kc * 2);
                    *(ushort4*)&sAh[o] = h;
                    *(ushort4*)&sAl[o] = l;
                }
            }
        }
        // ---------------- stage B tile ----------------
        {
            const int gn = n0 + srow;
            const ushort* gh = Bh + (size_t)gn * K + kt;
            const ushort* gl = Bl + (size_t)gn * K + kt;
#pragma unroll
            for (int j = 0; j < 4; ++j) {
                int kc = shalf * 32 + j * 8;
                bf16x8 vh = *(const bf16x8*)(gh + kc);
                bf16x8 vl = *(const bf16x8*)(gl + kc);
                int o = ldso(srow, kc * 2);
                *(bf16x8*)&sBh[o] = vh;
                *(bf16x8*)&sBl[o] = vl;
            }
        }
        __syncthreads();

#pragma unroll
        for (int ks = 0; ks < 2; ++ks) {
            bf16x8 fah[4], fal[4], fbh[4], fbl[4];
#pragma unroll
            for (int mi = 0; mi < 4; ++mi) {
                int rr = wr + mi * 16 + ln;
                int o = ldso(rr, ks * 64 + kg * 16);
                fah[mi] = *(const bf16x8*)&sAh[o];
                fal[mi] = *(const bf16x8*)&sAl[o];
            }
#pragma unroll
            for (int ni = 0; ni < 4; ++ni) {
                int rr = wc + ni * 16 + ln;
                int o = ldso(rr, ks * 64 + kg * 16);
                fbh[ni] = *(const bf16x8*)&sBh[o];
                fbl[ni] = *(const bf16x8*)&sBl[o];
            }
#pragma unroll
            for (int mi = 0; mi < 4; ++mi)
#pragma unroll
                for (int ni = 0; ni < 4; ++ni) {
                    acc[mi][ni] = __builtin_amdgcn_mfma_f32_16x16x32_bf16(
                        fah[mi], fbh[ni], acc[mi][ni], 0, 0, 0);
                    acc[mi][ni] = __builtin_amdgcn_mfma_f32_16x16x32_bf16(
                        fah[mi], fbl[ni], acc[mi][ni], 0, 0, 0);
                    acc[mi][ni] = __builtin_amdgcn_mfma_f32_16x16x32_bf16(
                        fal[mi], fbh[ni], acc[mi][ni], 0, 0, 0);
                }
        }
        __syncthreads();
    }

#pragma unroll
    for (int mi = 0; mi < 4; ++mi)
#pragma unroll
        for (int ni = 0; ni < 4; ++ni) {
            int col = n0 + wc + ni * 16 + ln;
            f32x4 a = acc[mi][ni];
#pragma unroll
            for (int j = 0; j < 4; ++j) {
                int row = m0 + wr + mi * 16 + kg * 4 + j;
                if (row < M) {
                    float v = a[j] + bias[col];
                    if (ACT == 1) v = geluf(v);
                    if (OUTP == 0) {
                        Cf[(size_t)row * N + col] = v;
                    } else {
                        ushort h, l;
                        bfsplit(v, h, l);
                        Ch[(size_t)row * N + col] = h;
                        Cl[(size_t)row * N + col] = l;
                    }
                }
            }
        }
}

// ---------------------------------------------------------------------------
__global__ __launch_bounds__(256) void k_wt(const float* __restrict__ W,
                                            ushort* __restrict__ WTh,
                                            ushort* __restrict__ WTl, int K, int N)
{
    __shared__ float t[32][33];
    const int k0 = blockIdx.x * 32, n0 = blockIdx.y * 32;
    const int c = threadIdx.x & 31, r8 = threadIdx.x >> 5;
#pragma unroll
    for (int i = 0; i < 4; ++i) {
        int r = r8 + i * 8;
        t[r][c] = W[(size_t)(k0 + r) * N + n0 + c];
    }
    __syncthreads();
#pragma unroll
    for (int i = 0; i < 4; ++i) {
        int r = r8 + i * 8;
        float v = t[c][r];
        ushort h, l;
        bfsplit(v, h, l);
        WTh[(size_t)(n0 + r) * K + k0 + c] = h;
        WTl[(size_t)(n0 + r) * K + k0 + c] = l;
    }
}

// folded pair W1: Wf[2304][768] from pW1[3072][768]
__global__ void k_fold(const float* __restrict__ pW1, float* __restrict__ Wf, int n)
{
    int i = blockIdx.x * blockDim.x + threadIdx.x;
    if (i >= n) return;
    int row = i / D;        // 0..2303
    float v;
    if (row < D)            v = pW1[i] - pW1[i + 1536 * D];
    else if (row < 2 * D)   v = pW1[i] + pW1[i + 768 * D];
    else                    v = pW1[i + 768 * D];
    Wf[i] = v;
}

__global__ __launch_bounds__(256) void k_entmean(
    const float* __restrict__ para, const int* __restrict__ mpos,
    const int* __restrict__ mid, int M, ushort* __restrict__ oh, ushort* __restrict__ ol)
{
    __shared__ int sb[2];
    const int e = blockIdx.x;
    if (threadIdx.x < 2) {
        int target = e + threadIdx.x;
        int lo = 0, hi = M;
        while (lo < hi) {
            int md = (lo + hi) >> 1;
            if (mid[md] < target) lo = md + 1; else hi = md;
        }
        sb[threadIdx.x] = lo;
    }
    __syncthreads();
    const int lo = sb[0], hi = sb[1];
    const int tid = threadIdx.x;
    float a0 = 0, a1 = 0, a2 = 0, b0 = 0, b1 = 0, b2 = 0;
    for (int m = lo; m < hi; ++m) {
        int p = mpos[m * 3], t1 = mpos[m * 3 + 1], t2 = mpos[m * 3 + 2];
        const float* L = para + (size_t)(p * LPARA + t1) * D;
        const float* R = para + (size_t)(p * LPARA + t2) * D;
        a0 += L[tid]; a1 += L[tid + 256]; a2 += L[tid + 512];
        b0 += R[tid]; b1 += R[tid + 256]; b2 += R[tid + 512];
    }
    const float inv = (hi > lo) ? 1.0f / (float)(hi - lo) : 0.0f;
    size_t base = (size_t)e * (2 * D);
    float vals[6] = { a0 * inv, a1 * inv, a2 * inv, b0 * inv, b1 * inv, b2 * inv };
    int offs[6] = { tid, tid + 256, tid + 512, D + tid, D + tid + 256, D + tid + 512 };
#pragma unroll
    for (int i = 0; i < 6; ++i) {
        ushort h, l;
        bfsplit(vals[i], h, l);
        oh[base + offs[i]] = h;
        ol[base + offs[i]] = l;
    }
}

__global__ void k_vecmat(const float* __restrict__ x, const float* __restrict__ W,
                         const float* __restrict__ b, float* __restrict__ out,
                         int K, int N, int act)
{
    int j = blockIdx.x * blockDim.x + threadIdx.x;
    if (j >= N) return;
    float s = 0.0f;
    for (int k = 0; k < K; ++k) s = fmaf(x[k], W[(size_t)k * N + j], s);
    s += b[j];
    if (act) s = geluf(s);
    out[j] = s;
}

__global__ void k_ctx(const float* __restrict__ cq, const float* __restrict__ qwh,
                      float* __restrict__ ctx)
{
    __shared__ float red[256];
    __shared__ float dist[LQ];
    const int tid = threadIdx.x;
    const int l = tid >> 3, part = tid & 7;
    float s = 0.0f;
    for (int d = part; d < D; d += 8) s += cq[d] * qwh[l * D + d];
    red[tid] = s;
    __syncthreads();
    if (part == 0) {
        float v = 0;
        for (int i = 0; i < 8; ++i) v += red[l * 8 + i];
        dist[l] = v;
    }
    __syncthreads();
    if (tid == 0) {
        float mx = -1e30f;
        for (int i = 0; i < LQ; ++i) mx = fmaxf(mx, dist[i]);
        float sm = 0;
        for (int i = 0; i < LQ; ++i) { float e = expf(dist[i] - mx); dist[i] = e; sm += e; }
        float inv = 1.0f / sm;
        for (int i = 0; i < LQ; ++i) dist[i] *= inv;
    }
    __syncthreads();
    for (int d = tid; d < D; d += 256) {
        float v = 0;
#pragma unroll
        for (int l2 = 0; l2 < LQ; ++l2) v += dist[l2] * qwh[l2 * D + d];
        ctx[d] = v + cq[d];
    }
}

__global__ void k_scalew(const float* __restrict__ ctx, const float* __restrict__ w1,
                         float* __restrict__ o, int n)
{
    int i = blockIdx.x * 256 + threadIdx.x;
    if (i < n) o[i] = ctx[i >> 8] * w1[i];
}

template <int PAIRMODE>
__global__ void k_rowdot(const float* __restrict__ H, const float* __restrict__ w2,
                         const float* __restrict__ sb2, int Nr,
                         float* __restrict__ simout,
                         const float* __restrict__ laste, const int* __restrict__ so,
                         float* __restrict__ newe)
{
    int r = blockIdx.x * 4 + (threadIdx.x >> 6);
    int lane = threadIdx.x & 63;
    if (r >= Nr) return;
    float s = 0.0f;
#pragma unroll
    for (int i = 0; i < 4; ++i)
        s += H[(size_t)r * 256 + lane + i * 64] * w2[lane + i * 64];
    for (int off = 32; off > 0; off >>= 1) s += __shfl_down(s, off, 64);
    if (lane == 0) {
        s += sb2[0];
        if (PAIRMODE == 0) {
            simout[r] = s;
        } else {
            float p = 1.0f / (1.0f + expf(-s));
            float v = laste[so[r * 2]] * p;
            atomicAdd(&newe[so[r * 2 + 1]], v);
        }
    }
}

__global__ void k_softmax(const float* __restrict__ sim, float* __restrict__ outp, int n)
{
    __shared__ float red[256];
    __shared__ float s_mx, s_sum;
    const int tid = threadIdx.x;
    float mx = -1e30f;
    for (int i = tid; i < n; i += 256) mx = fmaxf(mx, sim[i]);
    red[tid] = mx; __syncthreads();
    for (int off = 128; off > 0; off >>= 1) {
        if (tid < off) red[tid] = fmaxf(red[tid], red[tid + off]);
        __syncthreads();
    }
    if (tid == 0) s_mx = red[0];
    __syncthreads();
    const float mxv = s_mx;
    float sum = 0;
    for (int i = tid; i < n; i += 256) sum += expf(sim[i] - mxv);
    red[tid] = sum; __syncthreads();
    for (int off = 128; off > 0; off >>= 1) {
        if (tid < off) red[tid] += red[tid + off];
        __syncthreads();
    }
    if (tid == 0) s_sum = red[0];
    __syncthreads();
    const float inv = 1.0f / s_sum;
    for (int i = tid; i < n; i += 256) {
        float v = expf(sim[i] - mxv) * inv;
        outp[i] = v / fmaxf(v, 1.0f);
    }
}

__global__ void k_zero(float* p, int n)
{
    int i = blockIdx.x * blockDim.x + threadIdx.x;
    if (i < n) p[i] = 0.0f;
}

__global__ void k_clampstore(const float* __restrict__ ne, float* __restrict__ outp, int n)
{
    int i = blockIdx.x * blockDim.x + threadIdx.x;
    if (i < n) { float v = ne[i]; outp[i] = v / fmaxf(v, 1.0f); }
}

__global__ void k_final(const float* __restrict__ probs, const float* __restrict__ hlog,
                        float* __restrict__ out, int n)
{
    int i = blockIdx.x * blockDim.x + threadIdx.x;
    if (i >= n) return;
    float l0 = hlog[0], l1 = hlog[1], l2 = hlog[2];
    float m = fmaxf(l0, fmaxf(l1, l2));
    float e0 = expf(l0 - m), e1 = expf(l1 - m), e2 = expf(l2 - m);
    float inv = 1.0f / (e0 + e1 + e2);
    out[i] = (e0 * probs[i] + e1 * probs[n + i] + e2 * probs[2 * n + i]) * inv;
}

// ---------------------------------------------------------------------------
extern "C" void kernel_launch(void* const* d_in, const int* in_sizes, int n_in,
                              void* d_out, int out_size, void* d_ws, size_t ws_size,
                              hipStream_t stream)
{
    const size_t WS_NEED = 142790016;  // 136.2 MiB
    if (ws_size < WS_NEED) return;

    const float* para  = (const float*)d_in[0];
    const float* q     = (const float*)d_in[1];
    const float* qwh   = (const float*)d_in[2];
    const float* stW1  = (const float*)d_in[3];
    const float* stb1  = (const float*)d_in[4];
    const float* stW2  = (const float*)d_in[5];
    const float* stb2  = (const float*)d_in[6];
    const float* mW1   = (const float*)d_in[7];
    const float* mb1   = (const float*)d_in[8];
    const float* mW2   = (const float*)d_in[9];
    const float* mb2   = (const float*)d_in[10];
    const float* pW1   = (const float*)d_in[11];
    const float* pb1   = (const float*)d_in[12];
    const float* pW2   = (const float*)d_in[13];
    const float* pb2   = (const float*)d_in[14];
    const float* simW1 = (const float*)d_in[15];
    const float* simb1 = (const float*)d_in[16];
    const float* simW2 = (const float*)d_in[17];
    const float* simb2 = (const float*)d_in[18];
    const float* hW1   = (const float*)d_in[19];
    const float* hb1   = (const float*)d_in[20];
    const float* hW2   = (const float*)d_in[21];
    const float* hb2   = (const float*)d_in[22];
    const int*   mpos  = (const int*)d_in[23];
    const int*   mid   = (const int*)d_in[24];
    const int*   ppos  = (const int*)d_in[25];
    const int*   pso   = (const int*)d_in[26];

    // ---- workspace layout ----
    ushort* P1h  = (ushort*)d_ws;          // 15,360,000 (EM -> sub_feat -> pair_emb)
    ushort* P1l  = P1h  + 15360000;
    ushort* HIDh = P1l  + 15360000;        //  7,680,000 (hidden; H256 fp32 overlay)
    ushort* HIDl = HIDh + 7680000;
    ushort* Eh   = HIDl + 7680000;         //  7,680,000 (Wfold tmp -> ent_emb -> obj_feat)
    ushort* El   = Eh   + 7680000;
    ushort* mW1Th = El    + 7680000;       // 1,179,648 each
    ushort* mW1Tl = mW1Th + 1179648;
    ushort* mW2Th = mW1Tl + 1179648;       //   589,824 each
    ushort* mW2Tl = mW2Th + 589824;
    ushort* WfTh  = mW2Tl + 589824;        // 1,769,472 each ([768][2304] folded)
    ushort* WfTl  = WfTh  + 1769472;
    ushort* pW2Th = WfTl  + 1769472;       //   589,824 each
    ushort* pW2Tl = pW2Th + 589824;
    ushort* W1sTh0 = pW2Tl + 589824;       //   196,608 each x3 steps
    ushort* W1sTl0 = W1sTh0 + 3 * 196608;
    float*  W1s   = (float*)(W1sTl0 + 3 * 196608);  // 196,608 fp32
    float*  simb  = W1s  + 196608;
    float*  probs = simb + 20000;
    float*  newe  = probs + 30000;
    float*  h1    = newe + 10000;
    float*  cq    = h1   + 768;
    float*  ctx   = cq   + 768;
    float*  H256  = (float*)HIDh;          // 20000x256 fp32 overlay
    float*  Wfold = (float*)Eh;            // 1,769,472 fp32 tmp (dead before E written)

    dim3 B256(256);
    const ushort* np = nullptr;

    // 0) weight prep: fold pair W1, transpose+split all weights
    k_fold<<<(2304 * D + 255) / 256, B256, 0, stream>>>(pW1, Wfold, 2304 * D);
    k_wt<<<dim3(48, 24), B256, 0, stream>>>(mW1, mW1Th, mW1Tl, 2 * D, D);
    k_wt<<<dim3(24, 24), B256, 0, stream>>>(mW2, mW2Th, mW2Tl, D, D);
    k_wt<<<dim3(72, 24), B256, 0, stream>>>(Wfold, WfTh, WfTl, 3 * D, D);
    k_wt<<<dim3(24, 24), B256, 0, stream>>>(pW2, pW2Th, pW2Tl, D, D);

    // 1) per-step ctx -> scaled+transposed sim weights
    for (int t = 0; t < NSTEP; ++t) {
        k_vecmat<<<3, 256, 0, stream>>>(q, stW1 + (size_t)t * D * D, stb1 + t * D, h1, D, D, 1);
        k_vecmat<<<3, 256, 0, stream>>>(h1, stW2 + (size_t)t * D * D, stb2 + t * D, cq, D, D, 0);
        k_ctx<<<1, 256, 0, stream>>>(cq, qwh, ctx);
        k_scalew<<<768, 256, 0, stream>>>(ctx, simW1, W1s, D * 256);
        k_wt<<<dim3(24, 8), B256, 0, stream>>>(W1s, W1sTh0 + t * 196608, W1sTl0 + t * 196608,
                                               D, 256);
    }

    // 2) entity mention means -> P1 planes (10000 x 1536)
    k_entmean<<<NENT, 256, 0, stream>>>(para, mpos, mid, MMENT, P1h, P1l);

    // 3) ent_emb: gelu(EM@mW1) -> HID; HID@mW2 -> E
    gemm_m<0, 1, 1><<<474, B256, 0, stream>>>(P1h, P1l, nullptr, nullptr, 0, 0,
        np, np, np, np, mW1Th, mW1Tl, mb1, nullptr, HIDh, HIDl, NENT, D, 2 * D, 6);
    gemm_m<0, 0, 1><<<474, B256, 0, stream>>>(HIDh, HIDl, nullptr, nullptr, 0, 0,
        np, np, np, np, mW2Th, mW2Tl, mb2, nullptr, Eh, El, NENT, D, D, 6);

    // 4) step 0: sim on entities -> probs[0]   (E dead afterwards)
    gemm_m<0, 1, 0><<<158, B256, 0, stream>>>(Eh, El, nullptr, nullptr, 0, 0,
        np, np, np, np, W1sTh0, W1sTl0, simb1, H256, nullptr, nullptr, NENT, 256, D, 2);
    k_rowdot<0><<<NENT / 4, 256, 0, stream>>>(H256, simW2, simb2, NENT, simb,
                                              nullptr, nullptr, nullptr);
    k_softmax<<<1, 256, 0, stream>>>(simb, probs, NENT);

    // 5) pair pipeline, chunked; sub stages through P1, obj through E,
    //    pair_emb overwrites the sub chunk. Pair W1 is folded: K=2304.
    for (int c = 0; c < NPAIR / CHUNK; ++c) {
        const int* pp = ppos + (size_t)c * CHUNK * 5;
        ushort* sdh = P1h + (size_t)c * CHUNK * D;
        ushort* sdl = P1l + (size_t)c * CHUNK * D;
        gemm_m<1, 1, 1><<<474, B256, 0, stream>>>(np, np, para, pp, 1, 2,
            np, np, np, np, mW1Th, mW1Tl, mb1, nullptr, HIDh, HIDl, CHUNK, D, 2 * D, 6);
        gemm_m<0, 0, 1><<<474, B256, 0, stream>>>(HIDh, HIDl, nullptr, nullptr, 0, 0,
            np, np, np, np, mW2Th, mW2Tl, mb2, nullptr, sdh, sdl, CHUNK, D, D, 6);
        gemm_m<1, 1, 1><<<474, B256, 0, stream>>>(np, np, para, pp, 3, 4,
            np, np, np, np, mW1Th, mW1Tl, mb1, nullptr, HIDh, HIDl, CHUNK, D, 2 * D, 6);
        gemm_m<0, 0, 1><<<474, B256, 0, stream>>>(HIDh, HIDl, nullptr, nullptr, 0, 0,
            np, np, np, np, mW2Th, mW2Tl, mb2, nullptr, Eh, El, CHUNK, D, D, 6);
        gemm_m<2, 1, 1><<<474, B256, 0, stream>>>(np, np, nullptr, nullptr, 0, 0,
            sdh, sdl, Eh, El, WfTh, WfTl, pb1, nullptr, HIDh, HIDl, CHUNK, D, 3 * D, 6);
        gemm_m<0, 0, 1><<<474, B256, 0, stream>>>(HIDh, HIDl, nullptr, nullptr, 0, 0,
            np, np, np, np, pW2Th, pW2Tl, pb2, nullptr, sdh, sdl, CHUNK, D, D, 6);
    }

    // 6) steps 1,2: sim on pairs, scatter-propagate
    for (int t = 1; t < NSTEP; ++t) {
        gemm_m<0, 1, 0><<<314, B256, 0, stream>>>(P1h, P1l, nullptr, nullptr, 0, 0,
            np, np, np, np, W1sTh0 + t * 196608, W1sTl0 + t * 196608, simb1,
            H256, nullptr, nullptr, NPAIR, 256, D, 2);
        k_zero<<<40, 256, 0, stream>>>(newe, NENT);
        k_rowdot<1><<<NPAIR / 4, 256, 0, stream>>>(H256, simW2, simb2, NPAIR, nullptr,
                                                   probs + (t - 1) * NENT, pso, newe);
        k_clampstore<<<40, 256, 0, stream>>>(newe, probs + t * NENT, NENT);
    }

    // 7) hop attention + final mix
    k_vecmat<<<1, 256, 0, stream>>>(q, hW1, hb1, h1, D, 256, 1);
    k_vecmat<<<1, 256, 0, stream>>>(h1, hW2, hb2, cq, 256, 3, 0);
    k_final<<<40, 256, 0, stream>>>(probs, cq, (float*)d_out, NENT);
}